// Round 2
// baseline (226.199 us; speedup 1.0000x reference)
//
#include <hip/hip_runtime.h>

// Scaled dot-product attention, B=1 H=16 S=4096 D=64, fp32 in/out.
// Flash-attention: per block = 1 head x 128 q-rows; 4 waves x 32 q-rows each.
// QK^T computed swapped (S^T = mfma(K,Q)) so softmax is lane-local + 2 shuffles.
// bf16 MFMA (16x16x32), fp32 online softmax, P via per-wave LDS round-trip.

#define SQ 4096
#define DH 64
#define KVB 64
#define VSTRIDE 72  // V^T LDS stride: 9*c16+4g odd-multiplier -> 2-way (free) PV reads

// (1/sqrt(64)) * log2(e): fold scale+log2e into Q so p = exp2(s - m)
#define QSCALE 0.1803368801111204f

typedef __attribute__((ext_vector_type(8))) short short8;
typedef __attribute__((ext_vector_type(4))) short short4v;
typedef __attribute__((ext_vector_type(4))) float f32x4;

static __device__ __forceinline__ short f2b(float f) {
  __bf16 h = (__bf16)f;  // RNE convert; compiler fuses pairs into v_cvt_pk_bf16_f32
  return (short)__builtin_bit_cast(unsigned short, h);
}

static __device__ __forceinline__ float exp2_fast(float x) {
  return __builtin_amdgcn_exp2f(x);  // v_exp_f32
}

#define MFMA16(a, b, c) __builtin_amdgcn_mfma_f32_16x16x32_bf16((a), (b), (c), 0, 0, 0)

__global__ __launch_bounds__(256, 2) void attn_fwd(const float* __restrict__ Q,
                                                   const float* __restrict__ K,
                                                   const float* __restrict__ V,
                                                   float* __restrict__ O) {
  // K tile: [krow 64][d 64], XOR-swizzled (pos(d) = d ^ ((krow&7)*8)), b128-read clean
  __shared__ unsigned short Klds[64 * 64];
  // V^T tile: [d 64][krow 64 + pad], stride 72 (see above)
  __shared__ unsigned short Vtlds[64 * VSTRIDE];
  // P: per wave [qlocal 32][k 64], XOR-swizzled like K
  __shared__ unsigned short Plds[4 * 32 * 64];

  const int bid = blockIdx.x;
  // XCD-aware: xcd = bid&7; all 32 q-tiles of a head land on one XCD -> K/V in its L2
  const int h = (bid & 7) + 8 * (bid >> 8);
  const int qtile = (bid >> 3) & 31;
  const int tid = threadIdx.x;
  const int w = tid >> 6;
  const int lane = tid & 63;
  const int g = lane >> 4;    // 16-lane group
  const int c16 = lane & 15;

  const float* Qh = Q + h * SQ * DH;
  const float* Kh = K + h * SQ * DH;
  const float* Vh = V + h * SQ * DH;
  float* Oh = O + h * SQ * DH;

  const int qbase = qtile * 128 + w * 32;

  const f32x4 zero4 = {0.f, 0.f, 0.f, 0.f};

  // ---- Q fragments (B operand of S^T): qb[qt][c], lane: q = c16 (+16qt), d = 8g+32c..+7
  short8 qb[2][2];
#pragma unroll
  for (int qt = 0; qt < 2; ++qt) {
    const float* qr = Qh + (qbase + qt * 16 + c16) * DH + 8 * g;
#pragma unroll
    for (int c = 0; c < 2; ++c) {
      float4 a = *(const float4*)(qr + 32 * c);
      float4 b = *(const float4*)(qr + 32 * c + 4);
      short8 f;
      f[0] = f2b(a.x * QSCALE); f[1] = f2b(a.y * QSCALE);
      f[2] = f2b(a.z * QSCALE); f[3] = f2b(a.w * QSCALE);
      f[4] = f2b(b.x * QSCALE); f[5] = f2b(b.y * QSCALE);
      f[6] = f2b(b.z * QSCALE); f[7] = f2b(b.w * QSCALE);
      qb[qt][c] = f;
    }
  }

  f32x4 Oacc[2][4];
#pragma unroll
  for (int qt = 0; qt < 2; ++qt)
#pragma unroll
    for (int dt = 0; dt < 4; ++dt) Oacc[qt][dt] = zero4;
  float mrun[2] = {-INFINITY, -INFINITY};
  float lrun[2] = {0.f, 0.f};

  // staging map: thread covers rows sk..sk+3, cols sd..sd+3 of the 64x64 tile
  const int sk = 4 * (tid >> 4);
  const int sd = 4 * (tid & 15);

  for (int t = 0; t < SQ / KVB; ++t) {
    const int kv0 = t * KVB;
    __syncthreads();  // previous tile's compute done before overwrite

    // ---- stage K (row-major, swizzled) and V^T (transposed) as bf16
    {
      const float* kb = Kh + (kv0 + sk) * DH + sd;
      const float* vb = Vh + (kv0 + sk) * DH + sd;
      float4 k0 = *(const float4*)(kb + 0 * DH);
      float4 k1 = *(const float4*)(kb + 1 * DH);
      float4 k2 = *(const float4*)(kb + 2 * DH);
      float4 k3 = *(const float4*)(kb + 3 * DH);
      float4 v0 = *(const float4*)(vb + 0 * DH);
      float4 v1 = *(const float4*)(vb + 1 * DH);
      float4 v2 = *(const float4*)(vb + 2 * DH);
      float4 v3 = *(const float4*)(vb + 3 * DH);

      short4v a;
      a[0] = f2b(k0.x); a[1] = f2b(k0.y); a[2] = f2b(k0.z); a[3] = f2b(k0.w);
      *(short4v*)&Klds[(sk + 0) * 64 + (sd ^ (((sk + 0) & 7) * 8))] = a;
      a[0] = f2b(k1.x); a[1] = f2b(k1.y); a[2] = f2b(k1.z); a[3] = f2b(k1.w);
      *(short4v*)&Klds[(sk + 1) * 64 + (sd ^ (((sk + 1) & 7) * 8))] = a;
      a[0] = f2b(k2.x); a[1] = f2b(k2.y); a[2] = f2b(k2.z); a[3] = f2b(k2.w);
      *(short4v*)&Klds[(sk + 2) * 64 + (sd ^ (((sk + 2) & 7) * 8))] = a;
      a[0] = f2b(k3.x); a[1] = f2b(k3.y); a[2] = f2b(k3.z); a[3] = f2b(k3.w);
      *(short4v*)&Klds[(sk + 3) * 64 + (sd ^ (((sk + 3) & 7) * 8))] = a;

      short4v tv;
      tv[0] = f2b(v0.x); tv[1] = f2b(v1.x); tv[2] = f2b(v2.x); tv[3] = f2b(v3.x);
      *(short4v*)&Vtlds[(sd + 0) * VSTRIDE + sk] = tv;
      tv[0] = f2b(v0.y); tv[1] = f2b(v1.y); tv[2] = f2b(v2.y); tv[3] = f2b(v3.y);
      *(short4v*)&Vtlds[(sd + 1) * VSTRIDE + sk] = tv;
      tv[0] = f2b(v0.z); tv[1] = f2b(v1.z); tv[2] = f2b(v2.z); tv[3] = f2b(v3.z);
      *(short4v*)&Vtlds[(sd + 2) * VSTRIDE + sk] = tv;
      tv[0] = f2b(v0.w); tv[1] = f2b(v1.w); tv[2] = f2b(v2.w); tv[3] = f2b(v3.w);
      *(short4v*)&Vtlds[(sd + 3) * VSTRIDE + sk] = tv;
    }
    __syncthreads();

    // ---- S^T = K · Q^T : C[k_local][q_local], lane: q = c16, k = 4g+r (+16kt)
    f32x4 sA[2][4];
#pragma unroll
    for (int kt = 0; kt < 4; ++kt) {
      const int roff = (kt * 16 + c16) * 64;
      const int sw = (c16 & 7) * 8;
      short8 ka0 = *(const short8*)&Klds[roff + ((8 * g) ^ sw)];
      short8 ka1 = *(const short8*)&Klds[roff + ((8 * g + 32) ^ sw)];
      sA[0][kt] = MFMA16(ka0, qb[0][0], zero4);
      sA[0][kt] = MFMA16(ka1, qb[0][1], sA[0][kt]);
      sA[1][kt] = MFMA16(ka0, qb[1][0], zero4);
      sA[1][kt] = MFMA16(ka1, qb[1][1], sA[1][kt]);
    }

    // ---- online softmax (scores already in log2 domain), write P to LDS
#pragma unroll
    for (int qt = 0; qt < 2; ++qt) {
      float mx = sA[qt][0][0];
#pragma unroll
      for (int kt = 0; kt < 4; ++kt)
#pragma unroll
        for (int r = 0; r < 4; ++r) mx = fmaxf(mx, sA[qt][kt][r]);
      mx = fmaxf(mx, __shfl_xor(mx, 16));
      mx = fmaxf(mx, __shfl_xor(mx, 32));
      const float mnew = fmaxf(mrun[qt], mx);
      const float fsc = exp2_fast(mrun[qt] - mnew);
      mrun[qt] = mnew;

      float psum = 0.f;
      const int prow = (w * 32 + qt * 16 + c16) * 64;
      const int psw = (c16 & 7) * 8;
#pragma unroll
      for (int kt = 0; kt < 4; ++kt) {
        float p0 = exp2_fast(sA[qt][kt][0] - mnew);
        float p1 = exp2_fast(sA[qt][kt][1] - mnew);
        float p2 = exp2_fast(sA[qt][kt][2] - mnew);
        float p3 = exp2_fast(sA[qt][kt][3] - mnew);
        psum += (p0 + p1) + (p2 + p3);
        short4v pw;
        pw[0] = f2b(p0); pw[1] = f2b(p1); pw[2] = f2b(p2); pw[3] = f2b(p3);
        *(short4v*)&Plds[prow + ((4 * g + 16 * kt) ^ psw)] = pw;
      }
      psum += __shfl_xor(psum, 16);
      psum += __shfl_xor(psum, 32);
      lrun[qt] = lrun[qt] * fsc + psum;

      // O-rows live as q = 4g+r -> fetch this row's rescale factor from lane 4g+r
      const float f0 = __shfl(fsc, 4 * g + 0);
      const float f1 = __shfl(fsc, 4 * g + 1);
      const float f2 = __shfl(fsc, 4 * g + 2);
      const float f3 = __shfl(fsc, 4 * g + 3);
#pragma unroll
      for (int dt = 0; dt < 4; ++dt) {
        Oacc[qt][dt][0] *= f0;
        Oacc[qt][dt][1] *= f1;
        Oacc[qt][dt][2] *= f2;
        Oacc[qt][dt][3] *= f3;
      }
    }

    // ---- O += P · V  (A = P from Plds, B = V from Vtlds)
#pragma unroll
    for (int c = 0; c < 2; ++c) {
      const int koff = (8 * g + 32 * c) ^ ((c16 & 7) * 8);
      short8 pa0 = *(const short8*)&Plds[(w * 32 + c16) * 64 + koff];
      short8 pa1 = *(const short8*)&Plds[(w * 32 + 16 + c16) * 64 + koff];
#pragma unroll
      for (int dt = 0; dt < 4; ++dt) {
        const int vroff = (dt * 16 + c16) * VSTRIDE + 8 * g + 32 * c;
        short4v lo = *(const short4v*)&Vtlds[vroff];
        short4v hi = *(const short4v*)&Vtlds[vroff + 4];
        short8 vbf;
        vbf[0] = lo[0]; vbf[1] = lo[1]; vbf[2] = lo[2]; vbf[3] = lo[3];
        vbf[4] = hi[0]; vbf[5] = hi[1]; vbf[6] = hi[2]; vbf[7] = hi[3];
        Oacc[0][dt] = MFMA16(pa0, vbf, Oacc[0][dt]);
        Oacc[1][dt] = MFMA16(pa1, vbf, Oacc[1][dt]);
      }
    }
  }

  // ---- epilogue: normalize by 1/l (redistribute per O-row) and store
#pragma unroll
  for (int qt = 0; qt < 2; ++qt) {
    const float inv = 1.0f / lrun[qt];
    const float i0 = __shfl(inv, 4 * g + 0);
    const float i1 = __shfl(inv, 4 * g + 1);
    const float i2 = __shfl(inv, 4 * g + 2);
    const float i3 = __shfl(inv, 4 * g + 3);
#pragma unroll
    for (int dt = 0; dt < 4; ++dt) {
      float* op = Oh + (qbase + qt * 16 + 4 * g) * DH + dt * 16 + c16;
      op[0 * DH] = Oacc[qt][dt][0] * i0;
      op[1 * DH] = Oacc[qt][dt][1] * i1;
      op[2 * DH] = Oacc[qt][dt][2] * i2;
      op[3 * DH] = Oacc[qt][dt][3] * i3;
    }
  }
}

extern "C" void kernel_launch(void* const* d_in, const int* in_sizes, int n_in,
                              void* d_out, int out_size, void* d_ws, size_t ws_size,
                              hipStream_t stream) {
  const float* q = (const float*)d_in[0];
  const float* k = (const float*)d_in[1];
  const float* v = (const float*)d_in[2];
  float* o = (float*)d_out;
  attn_fwd<<<dim3(512), dim3(256), 0, stream>>>(q, k, v, o);
}

// Round 8
// 195.838 us; speedup vs baseline: 1.1550x; 1.1550x over previous
//
#include <hip/hip_runtime.h>

// Scaled dot-product attention, B=1 H=16 S=4096 D=64, fp32 in/out.
// Flash-attention. R4 restructure: 512-thread blocks = 8 waves x 16 q-rows
// (was 4 waves x 32) -> 4096 waves total = 16 waves/CU (4/SIMD), double the
// TLP of R2/R3, same staging cost per block (one 64x64 K/V tile per 128 q-rows).
// QK^T swapped (S^T = mfma(K,Q)) so softmax is lane-local + 2 shuffles.
// bf16 MFMA (16x16x32), fp32 online softmax, P via per-wave LDS round-trip.
// Carries R3: async double-buffered staging (1 barrier/tile), conflict-free
// V^T store map, defer-max (exact), setprio around MFMA clusters.

#define SQ 4096
#define DH 64
#define KVB 64
#define NT (SQ / KVB)
#define VSTRIDE 72  // V^T LDS stride: odd multiple of 4 banks -> 2-way (free) reads

// (1/sqrt(64)) * log2(e): fold scale+log2e into Q so p = exp2(s - m)
#define QSCALE 0.1803368801111204f

typedef __attribute__((ext_vector_type(8))) short short8;
typedef __attribute__((ext_vector_type(4))) short short4v;
typedef __attribute__((ext_vector_type(2))) short short2v;
typedef __attribute__((ext_vector_type(4))) float f32x4;

static __device__ __forceinline__ short f2b(float f) {
  __bf16 h = (__bf16)f;  // RNE convert; compiler fuses pairs into v_cvt_pk_bf16_f32
  return (short)__builtin_bit_cast(unsigned short, h);
}

static __device__ __forceinline__ float exp2_fast(float x) {
  return __builtin_amdgcn_exp2f(x);  // v_exp_f32
}

#define MFMA16(a, b, c) __builtin_amdgcn_mfma_f32_16x16x32_bf16((a), (b), (c), 0, 0, 0)

__global__ __launch_bounds__(512, 4) void attn_fwd(const float* __restrict__ Q,
                                                   const float* __restrict__ K,
                                                   const float* __restrict__ V,
                                                   float* __restrict__ O) {
  // K tile: [krow 64][d 64], XOR-swizzled (pos(d) = d ^ ((krow&7)*8)), b128-read clean
  __shared__ unsigned short Klds[2][64 * 64];
  // V^T tile: [d 64][krow 64 + pad], stride 72
  __shared__ unsigned short Vtlds[2][64 * VSTRIDE];
  // P: per wave [qlocal 16][k 64], XOR-swizzled like K
  __shared__ unsigned short Plds[8 * 16 * 64];

  const int bid = blockIdx.x;
  // XCD-aware: xcd = bid&7; all 32 q-tiles of a head land on one XCD -> K/V in its L2
  const int h = (bid & 7) + 8 * (bid >> 8);
  const int qtile = (bid >> 3) & 31;
  const int tid = threadIdx.x;
  const int w = tid >> 6;     // wave 0..7
  const int lane = tid & 63;
  const int g = lane >> 4;    // 16-lane group
  const int c16 = lane & 15;

  const float* Qh = Q + h * SQ * DH;
  const float* Kh = K + h * SQ * DH;
  const float* Vh = V + h * SQ * DH;
  float* Oh = O + h * SQ * DH;

  const int qbase = qtile * 128 + w * 16;  // 16 q-rows per wave

  const f32x4 zero4 = {0.f, 0.f, 0.f, 0.f};

  // ---- Q fragments (B operand of S^T): qb[c], lane: q = c16, d = 8g+32c..+7
  short8 qb[2];
  {
    const float* qr = Qh + (qbase + c16) * DH + 8 * g;
#pragma unroll
    for (int c = 0; c < 2; ++c) {
      float4 a = *(const float4*)(qr + 32 * c);
      float4 b = *(const float4*)(qr + 32 * c + 4);
      short8 f;
      f[0] = f2b(a.x * QSCALE); f[1] = f2b(a.y * QSCALE);
      f[2] = f2b(a.z * QSCALE); f[3] = f2b(a.w * QSCALE);
      f[4] = f2b(b.x * QSCALE); f[5] = f2b(b.y * QSCALE);
      f[6] = f2b(b.z * QSCALE); f[7] = f2b(b.w * QSCALE);
      qb[c] = f;
    }
  }

  f32x4 Oacc[4];
#pragma unroll
  for (int dt = 0; dt < 4; ++dt) Oacc[dt] = zero4;
  float mrun = -INFINITY;
  float lrun = 0.f;

  // K staging map (512 threads): rows sk..sk+1, cols sd..sd+3 of the 64x64 tile
  const int sk = 2 * (tid >> 4);      // 0..62
  const int sd = 4 * (tid & 15);      // 0..60
  // V staging map (swapped axes): rows skv..skv+1, cols sdv..sdv+3
  //   V^T store: row sdv+j, cols skv..skv+1 -> phase bank = const + (lane&31), clean
  const int skv = 2 * (tid & 31);     // 0..62
  const int sdv = 4 * (tid >> 5);     // 0..60 (tid>>5 in 0..15)

  // ---- register-staged tile load (issued early, written to LDS late)
  float4 k0, k1, v0, v1;
#define LOAD_TILE(kv0)                                  \
  {                                                     \
    const float* kb = Kh + ((kv0) + sk) * DH + sd;      \
    const float* vb = Vh + ((kv0) + skv) * DH + sdv;    \
    k0 = *(const float4*)(kb + 0 * DH);                 \
    k1 = *(const float4*)(kb + 1 * DH);                 \
    v0 = *(const float4*)(vb + 0 * DH);                 \
    v1 = *(const float4*)(vb + 1 * DH);                 \
  }

#define WRITE_TILE(b)                                                       \
  {                                                                         \
    short4v a;                                                              \
    a[0] = f2b(k0.x); a[1] = f2b(k0.y); a[2] = f2b(k0.z); a[3] = f2b(k0.w); \
    *(short4v*)&Klds[b][(sk + 0) * 64 + (sd ^ (((sk + 0) & 7) * 8))] = a;   \
    a[0] = f2b(k1.x); a[1] = f2b(k1.y); a[2] = f2b(k1.z); a[3] = f2b(k1.w); \
    *(short4v*)&Klds[b][(sk + 1) * 64 + (sd ^ (((sk + 1) & 7) * 8))] = a;   \
    short2v tv;                                                             \
    tv[0] = f2b(v0.x); tv[1] = f2b(v1.x);                                   \
    *(short2v*)&Vtlds[b][(sdv + 0) * VSTRIDE + skv] = tv;                   \
    tv[0] = f2b(v0.y); tv[1] = f2b(v1.y);                                   \
    *(short2v*)&Vtlds[b][(sdv + 1) * VSTRIDE + skv] = tv;                   \
    tv[0] = f2b(v0.z); tv[1] = f2b(v1.z);                                   \
    *(short2v*)&Vtlds[b][(sdv + 2) * VSTRIDE + skv] = tv;                   \
    tv[0] = f2b(v0.w); tv[1] = f2b(v1.w);                                   \
    *(short2v*)&Vtlds[b][(sdv + 3) * VSTRIDE + skv] = tv;                   \
  }

  // prologue: tile 0 -> buf 0
  LOAD_TILE(0)
  WRITE_TILE(0)
  int cur = 0;

  for (int t = 0; t < NT; ++t) {
    // One barrier per tile: makes buf[cur] writes visible AND guarantees all
    // waves finished compute t-1 (so writing buf[cur^1] below is race-free).
    __syncthreads();

    // ---- issue next tile's global loads (consumed only at WRITE_TILE below)
    const int tn = (t + 1 < NT) ? (t + 1) : t;  // last iter: redundant reload
    LOAD_TILE(tn * KVB)

    // ---- S^T = K . Q^T : C[k_local][q], lane: q = c16, k = 4g+r (+16kt)
    f32x4 sA[4];
    __builtin_amdgcn_s_setprio(1);
#pragma unroll
    for (int kt = 0; kt < 4; ++kt) {
      const int roff = (kt * 16 + c16) * 64;
      const int sw = (c16 & 7) * 8;
      short8 ka0 = *(const short8*)&Klds[cur][roff + ((8 * g) ^ sw)];
      short8 ka1 = *(const short8*)&Klds[cur][roff + ((8 * g + 32) ^ sw)];
      sA[kt] = MFMA16(ka0, qb[0], zero4);
      sA[kt] = MFMA16(ka1, qb[1], sA[kt]);
    }
    __builtin_amdgcn_s_setprio(0);

    // ---- online softmax (scores in log2 domain), write P to LDS
    {
      float mx = sA[0][0];
#pragma unroll
      for (int kt = 0; kt < 4; ++kt)
#pragma unroll
        for (int r = 0; r < 4; ++r) mx = fmaxf(mx, sA[kt][r]);
      mx = fmaxf(mx, __shfl_xor(mx, 16));
      mx = fmaxf(mx, __shfl_xor(mx, 32));

      // defer-max (exact): only rescale when some row's max actually grew
      if (!__all(mx <= mrun)) {
        const float mnew = fmaxf(mrun, mx);
        const float fsc = exp2_fast(mrun - mnew);
        mrun = mnew;
        lrun *= fsc;
        // O-rows live as q = 4g+r -> fetch this row's factor from lane 4g+r
        const float f0 = __shfl(fsc, 4 * g + 0);
        const float f1 = __shfl(fsc, 4 * g + 1);
        const float f2 = __shfl(fsc, 4 * g + 2);
        const float f3 = __shfl(fsc, 4 * g + 3);
#pragma unroll
        for (int dt = 0; dt < 4; ++dt) {
          Oacc[dt][0] *= f0;
          Oacc[dt][1] *= f1;
          Oacc[dt][2] *= f2;
          Oacc[dt][3] *= f3;
        }
      }

      const float mcur = mrun;
      float psum = 0.f;
      const int prow = (w * 16 + c16) * 64;
      const int psw = (c16 & 7) * 8;
#pragma unroll
      for (int kt = 0; kt < 4; ++kt) {
        float p0 = exp2_fast(sA[kt][0] - mcur);
        float p1 = exp2_fast(sA[kt][1] - mcur);
        float p2 = exp2_fast(sA[kt][2] - mcur);
        float p3 = exp2_fast(sA[kt][3] - mcur);
        psum += (p0 + p1) + (p2 + p3);
        short4v pw;
        pw[0] = f2b(p0); pw[1] = f2b(p1); pw[2] = f2b(p2); pw[3] = f2b(p3);
        *(short4v*)&Plds[prow + ((4 * g + 16 * kt) ^ psw)] = pw;
      }
      psum += __shfl_xor(psum, 16);
      psum += __shfl_xor(psum, 32);
      lrun += psum;
    }

    // ---- O += P . V  (A = P from Plds, B = V from Vtlds)
    __builtin_amdgcn_s_setprio(1);
#pragma unroll
    for (int c = 0; c < 2; ++c) {
      const int koff = (8 * g + 32 * c) ^ ((c16 & 7) * 8);
      short8 pa = *(const short8*)&Plds[(w * 16 + c16) * 64 + koff];
#pragma unroll
      for (int dt = 0; dt < 4; ++dt) {
        const int vroff = (dt * 16 + c16) * VSTRIDE + 8 * g + 32 * c;
        short4v lo = *(const short4v*)&Vtlds[cur][vroff];
        short4v hi = *(const short4v*)&Vtlds[cur][vroff + 4];
        short8 vbf;
        vbf[0] = lo[0]; vbf[1] = lo[1]; vbf[2] = lo[2]; vbf[3] = lo[3];
        vbf[4] = hi[0]; vbf[5] = hi[1]; vbf[6] = hi[2]; vbf[7] = hi[3];
        Oacc[dt] = MFMA16(pa, vbf, Oacc[dt]);
      }
    }
    __builtin_amdgcn_s_setprio(0);

    // ---- write next tile into the other buffer (vmcnt waits land here)
    WRITE_TILE(cur ^ 1)
    cur ^= 1;
  }

  // ---- epilogue: normalize by 1/l (redistribute per O-row) and store
  {
    const float inv = 1.0f / lrun;
    const float i0 = __shfl(inv, 4 * g + 0);
    const float i1 = __shfl(inv, 4 * g + 1);
    const float i2 = __shfl(inv, 4 * g + 2);
    const float i3 = __shfl(inv, 4 * g + 3);
#pragma unroll
    for (int dt = 0; dt < 4; ++dt) {
      float* op = Oh + (qbase + 4 * g) * DH + dt * 16 + c16;
      op[0 * DH] = Oacc[dt][0] * i0;
      op[1 * DH] = Oacc[dt][1] * i1;
      op[2 * DH] = Oacc[dt][2] * i2;
      op[3 * DH] = Oacc[dt][3] * i3;
    }
  }
}

extern "C" void kernel_launch(void* const* d_in, const int* in_sizes, int n_in,
                              void* d_out, int out_size, void* d_ws, size_t ws_size,
                              hipStream_t stream) {
  const float* q = (const float*)d_in[0];
  const float* k = (const float*)d_in[1];
  const float* v = (const float*)d_in[2];
  float* o = (float*)d_out;
  attn_fwd<<<dim3(512), dim3(512), 0, stream>>>(q, k, v, o);
}